// Round 6
// baseline (1054.764 us; speedup 1.0000x reference)
//
#include <hip/hip_runtime.h>

#define E_TOTAL 1600000
#define NN 100000
#define D 128      // node dim
#define ED 32      // edge dim
#define H 256      // hidden dim

typedef __attribute__((ext_vector_type(8))) short s16x8;   // 8 bf16 (one MFMA A/B frag)
typedef __attribute__((ext_vector_type(4))) short s16x4;
typedef __attribute__((ext_vector_type(4))) float f32x4;

#define MFMA(a, b, c) __builtin_amdgcn_mfma_f32_16x16x32_bf16((a), (b), (c), 0, 0, 0)

__device__ __forceinline__ short f2bf(float f) {
    unsigned u = __builtin_bit_cast(unsigned, f);
    u += 0x7fffu + ((u >> 16) & 1u);   // round-to-nearest-even
    return (short)(u >> 16);
}

// async global->LDS, 16B per lane; LDS dest is wave-uniform base (HW adds lane*16)
__device__ __forceinline__ void gll16(const void* g, void* l) {
    __builtin_amdgcn_global_load_lds(
        (const __attribute__((address_space(1))) void*)g,
        (__attribute__((address_space(3))) void*)l, 16, 0, 0);
}

// ---- prep: fp32 x -> bf16 ----
__global__ void k_cvt_x(const float* __restrict__ x, short* __restrict__ xb, int n) {
    int i = (blockIdx.x * blockDim.x + threadIdx.x) * 4;
    if (i >= n) return;
    f32x4 v = *(const f32x4*)(x + i);
    s16x4 o;
    o[0] = f2bf(v[0]); o[1] = f2bf(v[1]); o[2] = f2bf(v[2]); o[3] = f2bf(v[3]);
    *(s16x4*)(xb + i) = o;
}

// ---- prep: swizzle weight [K][N] fp32 into MFMA B-fragment order, bf16 ----
__global__ void k_swz(const float* __restrict__ W, short* __restrict__ out,
                      int K, int N, int total) {
    int idx = blockIdx.x * blockDim.x + threadIdx.x;
    if (idx >= total) return;
    int j    = idx & 7;
    int lane = (idx >> 3) & 63;
    int rest = idx >> 9;                // t*NT + nt
    int NT   = N >> 4;
    int nt   = rest % NT;
    int t    = rest / NT;
    int k    = t * 32 + (lane >> 4) * 8 + j;
    int col  = nt * 16 + (lane & 15);
    float v  = (k < K) ? W[k * N + col] : 0.f;
    out[idx] = f2bf(v);
}

// ---- sort prep: histogram of dst ----
__global__ void k_hist(const int* __restrict__ ei, int* __restrict__ cnt) {
    int e = blockIdx.x * blockDim.x + threadIdx.x;
    if (e >= E_TOTAL) return;
    atomicAdd(&cnt[ei[E_TOTAL + e]], 1);
}

// ---- hierarchical scan: per-block exclusive scan + block totals ----
__global__ void k_scan1(int* __restrict__ cnt, int* __restrict__ psum, int n) {
    __shared__ int wsum[16];
    __shared__ int woff[16];
    const int tid = threadIdx.x, lane = tid & 63, wv = tid >> 6;
    int i = blockIdx.x * 1024 + tid;
    int v = (i < n) ? cnt[i] : 0;
    int s = v;
#pragma unroll
    for (int off = 1; off < 64; off <<= 1) {
        int u = __shfl_up(s, off, 64);
        if (lane >= off) s += u;
    }
    if (lane == 63) wsum[wv] = s;
    __syncthreads();
    if (wv == 0 && lane < 16) {
        int t = wsum[lane];
        int sc = t;
#pragma unroll
        for (int off = 1; off < 16; off <<= 1) {
            int u = __shfl_up(sc, off, 16);
            if (lane >= off) sc += u;
        }
        woff[lane] = sc - t;
    }
    __syncthreads();
    int excl = (s - v) + woff[wv];
    if (i < n) cnt[i] = excl;
    if (tid == 1023) psum[blockIdx.x] = excl + v;   // block total
}

// ---- scan the block totals (one small block) ----
__global__ void k_scan2(int* __restrict__ psum, int nb) {
    __shared__ int w0;
    const int tid = threadIdx.x, lane = tid & 63, wv = tid >> 6;
    int v = (tid < nb) ? psum[tid] : 0;
    int s = v;
#pragma unroll
    for (int off = 1; off < 64; off <<= 1) {
        int u = __shfl_up(s, off, 64);
        if (lane >= off) s += u;
    }
    if (wv == 0 && lane == 63) w0 = s;
    __syncthreads();
    int excl = (s - v) + (wv ? w0 : 0);
    if (tid < nb) psum[tid] = excl;
}

// ---- add block offsets back ----
__global__ void k_scan3(const int* __restrict__ psum, int* __restrict__ cnt, int n) {
    int i = blockIdx.x * 1024 + threadIdx.x;
    if (i < n) cnt[i] += psum[blockIdx.x];
}

// ---- sort prep: scatter edges into dst-sorted order ----
__global__ void k_perm(const int* __restrict__ ei, int* __restrict__ cursor,
                       int* __restrict__ perm, int2* __restrict__ srcdst) {
    int e = blockIdx.x * blockDim.x + threadIdx.x;
    if (e >= E_TOTAL) return;
    int s = ei[e], d = ei[E_TOTAL + e];
    int pos = atomicAdd(&cursor[d], 1);
    perm[pos] = e;
    srcdst[pos] = make_int2(s, d);
}

// ---- edge MLP + segment-reduced scatter-add: A-stationary, fat waves ----
// 256 thr / 4 waves / 128 sorted edges per block. A (128 x 320 bf16, swizzled
// chunks of [128 edges][64B]) staged once; wave w owns 64 l1 output cols
// (4 B-frags per A-read -> half the LDS read traffic of the 8-wave version)
// and 32 l2 cols. Zero barriers inside K-loops. acc[8][4] = 128 VGPR ->
// 2 waves/SIMD, 2 blocks/CU. Swizzle identical to the verified v5 layout.
__global__ __launch_bounds__(256, 2)
void k_edge(const short* __restrict__ xb, const int* __restrict__ perm,
            const int2* __restrict__ srcdst,
            const float* __restrict__ eattr, const float* __restrict__ cong,
            const short* __restrict__ W1s, const float* __restrict__ b1,
            const short* __restrict__ W2s, const float* __restrict__ b2,
            float* __restrict__ agg) {
    __shared__ char smem[73728];     // A: 9 x [128][64B]; h + mbuf alias it
    __shared__ int   dst_s[128];
    __shared__ short cong_s[128];

    const int tid  = threadIdx.x;
    const int lane = tid & 63;
    const int w    = tid >> 6;       // wave 0..3
    const int m    = lane & 15;
    const int q    = lane >> 4;
    const int p0b  = blockIdx.x * 128;

    // ---- stage A (once per block); each wave stages 2 x 16-edge regions ----
    {
        const int kqs = (lane & 3) ^ ((lane >> 4) & 3);   // data-slot for phys slot lane&3
#pragma unroll
        for (int j = 0; j < 2; j++) {
            int el  = w * 32 + j * 16 + (lane >> 2);
            int2 sd = srcdst[p0b + el];
            int  ea = perm[p0b + el];
            char* dst = smem + (w * 2 + j) * 1024;
            const char* gx0 = (const char*)xb + (long)sd.x * 256 + kqs * 16;
            const char* gx1 = (const char*)xb + (long)sd.y * 256 + kqs * 16;
#pragma unroll
            for (int t = 0; t < 4; t++)                   // x[src]: chunks 0..3
                gll16(gx0 + t * 64, dst + t * 8192);
#pragma unroll
            for (int t = 0; t < 4; t++)                   // x[dst]: chunks 4..7
                gll16(gx1 + t * 64, dst + (4 + t) * 8192);
            // chunk 8: eattr (fp32 -> bf16 via regs)
            const float* ge = eattr + (long)ea * ED + kqs * 8;
            f32x4 e0 = *(const f32x4*)ge, e1 = *(const f32x4*)(ge + 4);
            s16x8 ev;
#pragma unroll
            for (int jj = 0; jj < 4; jj++) { ev[jj] = f2bf(e0[jj]); ev[4 + jj] = f2bf(e1[jj]); }
            *(s16x8*)(dst + 8 * 8192 + lane * 16) = ev;
        }
        if (tid < 128) {
            int2 sd2 = srcdst[p0b + tid];
            dst_s[tid]  = sd2.y;
            cong_s[tid] = f2bf(cong[sd2.x]);
        }
    }
    __syncthreads();

    const int rdoff = m * 64 + ((q ^ ((m >> 2) & 3)) << 4);   // swizzled A-read offset

    // ---- layer 1: 128 edges x wave's 64 cols, no barriers ----
    f32x4 acc[8][4];
#pragma unroll
    for (int mt = 0; mt < 8; mt++)
#pragma unroll
        for (int n = 0; n < 4; n++) acc[mt][n] = (f32x4){0.f, 0.f, 0.f, 0.f};

#pragma unroll
    for (int t = 0; t < 9; t++) {
        s16x8 b[4];
        const short* bw = W1s + (t * 16 + w * 4) * 512 + lane * 8;
#pragma unroll
        for (int n = 0; n < 4; n++) b[n] = *(const s16x8*)(bw + n * 512);
#pragma unroll
        for (int mt = 0; mt < 8; mt++) {
            s16x8 a = *(const s16x8*)(smem + t * 8192 + mt * 1024 + rdoff);
#pragma unroll
            for (int n = 0; n < 4; n++) acc[mt][n] = MFMA(a, b[n], acc[mt][n]);
        }
    }
    {   // t=9: congestion feature (k=288) — A synthesized from cong_s
        s16x8 b[4];
        const short* bw = W1s + (9 * 16 + w * 4) * 512 + lane * 8;
#pragma unroll
        for (int n = 0; n < 4; n++) b[n] = *(const s16x8*)(bw + n * 512);
#pragma unroll
        for (int mt = 0; mt < 8; mt++) {
            s16x8 a = (s16x8){0, 0, 0, 0, 0, 0, 0, 0};
            short cv = cong_s[mt * 16 + m];
            a[0] = (q == 0) ? cv : (short)0;
#pragma unroll
            for (int n = 0; n < 4; n++) acc[mt][n] = MFMA(a, b[n], acc[mt][n]);
        }
    }
    __syncthreads();      // all A-reads done -> safe to overwrite with h

    // ---- h-write: +bias, relu, bf16 -> chunks 2w, 2w+1 (same swizzled layout) ----
    {
        short* hb = (short*)smem;
#pragma unroll
        for (int n = 0; n < 4; n++) {
            const int chunk = 2 * w + (n >> 1);
            const int srq   = (n & 1) * 2 + (m >> 3);
            const int phys  = srq ^ q;                    // write key(e) = q
            const float bias = b1[w * 64 + n * 16 + m];
            const int base = chunk * 4096 + (q * 4) * 32 + phys * 8 + (m & 7);
#pragma unroll
            for (int mt = 0; mt < 8; mt++) {
#pragma unroll
                for (int r = 0; r < 4; r++) {
                    float v = acc[mt][n][r] + bias;
                    hb[base + mt * 512 + r * 32] = f2bf(v > 0.f ? v : 0.f);
                }
            }
        }
    }
    __syncthreads();

    // ---- layer 2: K=256 over h, wave owns 32 out-cols, no barriers ----
    f32x4 acc2[8][2];
#pragma unroll
    for (int mt = 0; mt < 8; mt++) {
        acc2[mt][0] = (f32x4){0.f, 0.f, 0.f, 0.f};
        acc2[mt][1] = (f32x4){0.f, 0.f, 0.f, 0.f};
    }
#pragma unroll
    for (int t2 = 0; t2 < 8; t2++) {
        s16x8 b0  = *(const s16x8*)(W2s + (t2 * 8 + w * 2) * 512 + lane * 8);
        s16x8 b1v = *(const s16x8*)(W2s + (t2 * 8 + w * 2 + 1) * 512 + lane * 8);
#pragma unroll
        for (int mt = 0; mt < 8; mt++) {
            s16x8 a = *(const s16x8*)(smem + t2 * 8192 + mt * 1024 + rdoff);
            acc2[mt][0] = MFMA(a, b0, acc2[mt][0]);
            acc2[mt][1] = MFMA(a, b1v, acc2[mt][1]);
        }
    }
    __syncthreads();      // h dead -> mbuf may alias

    // ---- messages -> mbuf ----
    {
        float (*mbuf)[132] = (float (*)[132])smem;
        float bb0 = b2[w * 32 + m];
        float bb1 = b2[w * 32 + 16 + m];
#pragma unroll
        for (int mt = 0; mt < 8; mt++)
#pragma unroll
            for (int r = 0; r < 4; r++) {
                mbuf[mt * 16 + q * 4 + r][w * 32 + m]      = acc2[mt][0][r] + bb0;
                mbuf[mt * 16 + q * 4 + r][w * 32 + 16 + m] = acc2[mt][1][r] + bb1;
            }
    }
    __syncthreads();

    // ---- segment-reduce 128 sorted rows (two 64-row halves; atomics fix seams) ----
    {
        float (*mbuf)[132] = (float (*)[132])smem;
        const int half = tid >> 7, cc = tid & 127;
        float s = 0.f;
        int prev = dst_s[half * 64];
        for (int row = half * 64; row < half * 64 + 64; row++) {
            int dcur = dst_s[row];
            if (dcur != prev) {
                __hip_atomic_fetch_add(agg + (long)prev * D + cc, s,
                                       __ATOMIC_RELAXED, __HIP_MEMORY_SCOPE_AGENT);
                s = 0.f; prev = dcur;
            }
            s += mbuf[row][cc];
        }
        __hip_atomic_fetch_add(agg + (long)prev * D + cc, s,
                               __ATOMIC_RELAXED, __HIP_MEMORY_SCOPE_AGENT);
    }
}

// ---- node MLP: same A-stationary fat-wave structure ----
__global__ __launch_bounds__(256, 2)
void k_node(const short* __restrict__ xb, const float* __restrict__ agg,
            const short* __restrict__ U1s, const float* __restrict__ b1,
            const short* __restrict__ U2s, const float* __restrict__ b2,
            float* __restrict__ out) {
    __shared__ char smem[65536];     // A: 8 x [128][64B]; h aliases
    const int tid  = threadIdx.x;
    const int lane = tid & 63;
    const int w    = tid >> 6;
    const int m    = lane & 15;
    const int q    = lane >> 4;
    const int r0   = blockIdx.x * 128;

    {
        const int kqs = (lane & 3) ^ ((lane >> 4) & 3);
#pragma unroll
        for (int j = 0; j < 2; j++) {
            int rowl = w * 32 + j * 16 + (lane >> 2);
            int grow = r0 + rowl;
            int gc   = grow < NN ? grow : 0;              // clamp; stores guarded
            char* dst = smem + (w * 2 + j) * 1024;
            const char* gx = (const char*)xb + (long)gc * 256 + kqs * 16;
#pragma unroll
            for (int t = 0; t < 4; t++)                   // x: chunks 0..3
                gll16(gx + t * 64, dst + t * 8192);
            const float* ga = agg + (long)gc * D + kqs * 8;
#pragma unroll
            for (int t = 0; t < 4; t++) {                 // agg (fp32->bf16): chunks 4..7
                f32x4 a0 = *(const f32x4*)(ga + t * 32);
                f32x4 a1 = *(const f32x4*)(ga + t * 32 + 4);
                s16x8 v;
#pragma unroll
                for (int jj = 0; jj < 4; jj++) { v[jj] = f2bf(a0[jj]); v[4 + jj] = f2bf(a1[jj]); }
                *(s16x8*)(dst + (4 + t) * 8192 + lane * 16) = v;
            }
        }
    }
    __syncthreads();

    const int rdoff = m * 64 + ((q ^ ((m >> 2) & 3)) << 4);

    f32x4 acc[8][4];
#pragma unroll
    for (int mt = 0; mt < 8; mt++)
#pragma unroll
        for (int n = 0; n < 4; n++) acc[mt][n] = (f32x4){0.f, 0.f, 0.f, 0.f};

#pragma unroll
    for (int t = 0; t < 8; t++) {
        s16x8 b[4];
        const short* bw = U1s + (t * 16 + w * 4) * 512 + lane * 8;
#pragma unroll
        for (int n = 0; n < 4; n++) b[n] = *(const s16x8*)(bw + n * 512);
#pragma unroll
        for (int mt = 0; mt < 8; mt++) {
            s16x8 a = *(const s16x8*)(smem + t * 8192 + mt * 1024 + rdoff);
#pragma unroll
            for (int n = 0; n < 4; n++) acc[mt][n] = MFMA(a, b[n], acc[mt][n]);
        }
    }
    __syncthreads();

    {
        short* hb = (short*)smem;
#pragma unroll
        for (int n = 0; n < 4; n++) {
            const int chunk = 2 * w + (n >> 1);
            const int srq   = (n & 1) * 2 + (m >> 3);
            const int phys  = srq ^ q;
            const float bias = b1[w * 64 + n * 16 + m];
            const int base = chunk * 4096 + (q * 4) * 32 + phys * 8 + (m & 7);
#pragma unroll
            for (int mt = 0; mt < 8; mt++) {
#pragma unroll
                for (int r = 0; r < 4; r++) {
                    float v = acc[mt][n][r] + bias;
                    hb[base + mt * 512 + r * 32] = f2bf(v > 0.f ? v : 0.f);
                }
            }
        }
    }
    __syncthreads();

    f32x4 acc2[8][2];
#pragma unroll
    for (int mt = 0; mt < 8; mt++) {
        acc2[mt][0] = (f32x4){0.f, 0.f, 0.f, 0.f};
        acc2[mt][1] = (f32x4){0.f, 0.f, 0.f, 0.f};
    }
#pragma unroll
    for (int t2 = 0; t2 < 8; t2++) {
        s16x8 b0  = *(const s16x8*)(U2s + (t2 * 8 + w * 2) * 512 + lane * 8);
        s16x8 b1v = *(const s16x8*)(U2s + (t2 * 8 + w * 2 + 1) * 512 + lane * 8);
#pragma unroll
        for (int mt = 0; mt < 8; mt++) {
            s16x8 a = *(const s16x8*)(smem + t2 * 8192 + mt * 1024 + rdoff);
            acc2[mt][0] = MFMA(a, b0, acc2[mt][0]);
            acc2[mt][1] = MFMA(a, b1v, acc2[mt][1]);
        }
    }

    {
        float bb0 = b2[w * 32 + m];
        float bb1 = b2[w * 32 + 16 + m];
#pragma unroll
        for (int mt = 0; mt < 8; mt++)
#pragma unroll
            for (int r = 0; r < 4; r++) {
                int grow = r0 + mt * 16 + q * 4 + r;
                if (grow < NN) {
                    out[(long)grow * D + w * 32 + m]      = acc2[mt][0][r] + bb0;
                    out[(long)grow * D + w * 32 + 16 + m] = acc2[mt][1][r] + bb1;
                }
            }
    }
}

extern "C" void kernel_launch(void* const* d_in, const int* in_sizes, int n_in,
                              void* d_out, int out_size, void* d_ws, size_t ws_size,
                              hipStream_t stream) {
    const float* x     = (const float*)d_in[0];
    const int*   ei    = (const int*)d_in[1];
    const float* eattr = (const float*)d_in[2];
    const float* cong  = (const float*)d_in[3];
    const float* mW1   = (const float*)d_in[4];
    const float* mb1   = (const float*)d_in[5];
    const float* mW2   = (const float*)d_in[6];
    const float* mb2   = (const float*)d_in[7];
    const float* uW1   = (const float*)d_in[8];
    const float* ub1   = (const float*)d_in[9];
    const float* uW2   = (const float*)d_in[10];
    const float* ub2   = (const float*)d_in[11];

    char* ws = (char*)d_ws;
    float* agg    = (float*)ws;                     // 51,200,000 B
    short* xb     = (short*)(ws + 51200000);        // 25,600,000 B
    short* W1s    = (short*)(ws + 76800000);        //    163,840 B (K padded 289->320)
    short* W2s    = (short*)(ws + 76963840);        //     65,536 B
    short* U1s    = (short*)(ws + 77029376);        //    131,072 B
    short* U2s    = (short*)(ws + 77160448);        //     65,536 B
    int*   cnt    = (int*)(ws + 77225984);          //    400,000 B (cursor after scan)
    int*   perm   = (int*)(ws + 77625984);          //  6,400,000 B
    int2*  srcdst = (int2*)(ws + 84025984);         // 12,800,000 B
    int*   psum   = (int*)(ws + 96825984);          //        512 B (block partials)

    hipMemsetAsync(agg, 0, (size_t)NN * D * sizeof(float), stream);
    hipMemsetAsync(cnt, 0, (size_t)NN * sizeof(int), stream);

    k_cvt_x<<<(NN * D / 4 + 255) / 256, 256, 0, stream>>>(x, xb, NN * D);

    int tW1 = 10 * 16 * 512, tW2 = 8 * 8 * 512, tU1 = 8 * 16 * 512, tU2 = 8 * 8 * 512;
    k_swz<<<(tW1 + 255) / 256, 256, 0, stream>>>(mW1, W1s, 289, 256, tW1);
    k_swz<<<(tW2 + 255) / 256, 256, 0, stream>>>(mW2, W2s, 256, 128, tW2);
    k_swz<<<(tU1 + 255) / 256, 256, 0, stream>>>(uW1, U1s, 256, 256, tU1);
    k_swz<<<(tU2 + 255) / 256, 256, 0, stream>>>(uW2, U2s, 256, 128, tU2);

    // counting sort by dst (hierarchical scan)
    int nb = (NN + 1023) / 1024;   // 98
    k_hist<<<(E_TOTAL + 255) / 256, 256, 0, stream>>>(ei, cnt);
    k_scan1<<<nb, 1024, 0, stream>>>(cnt, psum, NN);
    k_scan2<<<1, 128, 0, stream>>>(psum, nb);
    k_scan3<<<nb, 1024, 0, stream>>>(psum, cnt, NN);
    k_perm<<<(E_TOTAL + 255) / 256, 256, 0, stream>>>(ei, cnt, perm, srcdst);

    // 128 sorted edges per 256-thread block (4 fat waves, 64 cols each)
    k_edge<<<E_TOTAL / 128, 256, 0, stream>>>(xb, perm, srcdst, eattr, cong,
                                              W1s, mb1, W2s, mb2, agg);
    // 128 rows per 256-thread block
    k_node<<<(NN + 127) / 128, 256, 0, stream>>>(xb, agg, U1s, ub1, U2s, ub2,
                                                 (float*)d_out);
}

// Round 7
// 946.955 us; speedup vs baseline: 1.1138x; 1.1138x over previous
//
#include <hip/hip_runtime.h>

#define E_TOTAL 1600000
#define NN 100000
#define D 128      // node dim
#define ED 32      // edge dim
#define H 256      // hidden dim

typedef __attribute__((ext_vector_type(8))) short s16x8;   // 8 bf16 (one MFMA A/B frag)
typedef __attribute__((ext_vector_type(4))) short s16x4;
typedef __attribute__((ext_vector_type(4))) float f32x4;

#define MFMA(a, b, c) __builtin_amdgcn_mfma_f32_16x16x32_bf16((a), (b), (c), 0, 0, 0)

__device__ __forceinline__ short f2bf(float f) {
    unsigned u = __builtin_bit_cast(unsigned, f);
    u += 0x7fffu + ((u >> 16) & 1u);   // round-to-nearest-even
    return (short)(u >> 16);
}

// async global->LDS, 16B per lane; LDS dest is wave-uniform base (HW adds lane*16)
__device__ __forceinline__ void gll16(const void* g, void* l) {
    __builtin_amdgcn_global_load_lds(
        (const __attribute__((address_space(1))) void*)g,
        (__attribute__((address_space(3))) void*)l, 16, 0, 0);
}

// ---- prep: fp32 x -> bf16 ----
__global__ void k_cvt_x(const float* __restrict__ x, short* __restrict__ xb, int n) {
    int i = (blockIdx.x * blockDim.x + threadIdx.x) * 4;
    if (i >= n) return;
    f32x4 v = *(const f32x4*)(x + i);
    s16x4 o;
    o[0] = f2bf(v[0]); o[1] = f2bf(v[1]); o[2] = f2bf(v[2]); o[3] = f2bf(v[3]);
    *(s16x4*)(xb + i) = o;
}

// ---- prep: swizzle weight [K][N] fp32 into MFMA B-fragment order, bf16 ----
__global__ void k_swz(const float* __restrict__ W, short* __restrict__ out,
                      int K, int N, int total) {
    int idx = blockIdx.x * blockDim.x + threadIdx.x;
    if (idx >= total) return;
    int j    = idx & 7;
    int lane = (idx >> 3) & 63;
    int rest = idx >> 9;                // t*NT + nt
    int NT   = N >> 4;
    int nt   = rest % NT;
    int t    = rest / NT;
    int k    = t * 32 + (lane >> 4) * 8 + j;
    int col  = nt * 16 + (lane & 15);
    float v  = (k < K) ? W[k * N + col] : 0.f;
    out[idx] = f2bf(v);
}

// ---- sort prep: histogram of dst ----
__global__ void k_hist(const int* __restrict__ ei, int* __restrict__ cnt) {
    int e = blockIdx.x * blockDim.x + threadIdx.x;
    if (e >= E_TOTAL) return;
    atomicAdd(&cnt[ei[E_TOTAL + e]], 1);
}

// ---- hierarchical scan: per-block exclusive scan + block totals ----
__global__ void k_scan1(int* __restrict__ cnt, int* __restrict__ psum, int n) {
    __shared__ int wsum[16];
    __shared__ int woff[16];
    const int tid = threadIdx.x, lane = tid & 63, wv = tid >> 6;
    int i = blockIdx.x * 1024 + tid;
    int v = (i < n) ? cnt[i] : 0;
    int s = v;
#pragma unroll
    for (int off = 1; off < 64; off <<= 1) {
        int u = __shfl_up(s, off, 64);
        if (lane >= off) s += u;
    }
    if (lane == 63) wsum[wv] = s;
    __syncthreads();
    if (wv == 0 && lane < 16) {
        int t = wsum[lane];
        int sc = t;
#pragma unroll
        for (int off = 1; off < 16; off <<= 1) {
            int u = __shfl_up(sc, off, 16);
            if (lane >= off) sc += u;
        }
        woff[lane] = sc - t;
    }
    __syncthreads();
    int excl = (s - v) + woff[wv];
    if (i < n) cnt[i] = excl;
    if (tid == 1023) psum[blockIdx.x] = excl + v;   // block total
}

// ---- scan the block totals (one small block) ----
__global__ void k_scan2(int* __restrict__ psum, int nb) {
    __shared__ int w0;
    const int tid = threadIdx.x, lane = tid & 63, wv = tid >> 6;
    int v = (tid < nb) ? psum[tid] : 0;
    int s = v;
#pragma unroll
    for (int off = 1; off < 64; off <<= 1) {
        int u = __shfl_up(s, off, 64);
        if (lane >= off) s += u;
    }
    if (wv == 0 && lane == 63) w0 = s;
    __syncthreads();
    int excl = (s - v) + (wv ? w0 : 0);
    if (tid < nb) psum[tid] = excl;
}

// ---- add block offsets back ----
__global__ void k_scan3(const int* __restrict__ psum, int* __restrict__ cnt, int n) {
    int i = blockIdx.x * 1024 + threadIdx.x;
    if (i < n) cnt[i] += psum[blockIdx.x];
}

// ---- sort prep: scatter edges into dst-sorted order ----
__global__ void k_perm(const int* __restrict__ ei, int* __restrict__ cursor,
                       int* __restrict__ perm, int2* __restrict__ srcdst) {
    int e = blockIdx.x * blockDim.x + threadIdx.x;
    if (e >= E_TOTAL) return;
    int s = ei[e], d = ei[E_TOTAL + e];
    int pos = atomicAdd(&cursor[d], 1);
    perm[pos] = e;
    srcdst[pos] = make_int2(s, d);
}

// ---- edge MLP + segment-reduced scatter-add: A-stationary, zero-barrier K-loops ----
// Round-5 geometry (512 thr / 8 waves / 128 sorted edges; wave owns 32 l1 cols,
// 16 l2 cols; occupancy 45%) with a CONFLICT-FREE swizzle: key(edge)=(edge>>1)&3
// (was (edge>>2)&3). Within each 8-lane LDS dispatch group the 16B slots now
// cycle 0,0,1,1,2,2,3,3 so banks (m&1)*16 + phys*4 + 0..3 cover all 32 exactly
// once -> ds_read_b128 conflict-free (was structurally 2-way).
__global__ __launch_bounds__(512, 4)
void k_edge(const short* __restrict__ xb, const int* __restrict__ perm,
            const int2* __restrict__ srcdst,
            const float* __restrict__ eattr, const float* __restrict__ cong,
            const short* __restrict__ W1s, const float* __restrict__ b1,
            const short* __restrict__ W2s, const float* __restrict__ b2,
            float* __restrict__ agg) {
    __shared__ char smem[73728];     // A: 9 x [128 edges][64B]; h + mbuf alias it
    __shared__ int   dst_s[128];
    __shared__ short cong_s[128];

    const int tid  = threadIdx.x;
    const int lane = tid & 63;
    const int w    = tid >> 6;       // wave 0..7
    const int m    = lane & 15;
    const int q    = lane >> 4;
    const int p0b  = blockIdx.x * 128;

    // ---- stage A (once per block) ----
    {
        int edge = w * 16 + (lane >> 2);              // wave w stages rows w*16..+16
        int2 sd  = srcdst[p0b + edge];
        int kqs  = (lane & 3) ^ ((lane >> 3) & 3);    // pre-swizzled source slot (new key)
        const char* gx0 = (const char*)xb + (long)sd.x * 256 + kqs * 16;
        const char* gx1 = (const char*)xb + (long)sd.y * 256 + kqs * 16;
#pragma unroll
        for (int t = 0; t < 4; t++)                   // x[src]: chunks 0..3
            gll16(gx0 + t * 64, smem + t * 8192 + w * 1024);
#pragma unroll
        for (int t = 0; t < 4; t++)                   // x[dst]: chunks 4..7
            gll16(gx1 + t * 64, smem + (4 + t) * 8192 + w * 1024);
        // chunk 8: eattr (fp32 -> bf16 via regs)
        int ea = perm[p0b + edge];
        const float* ge = eattr + (long)ea * ED + kqs * 8;
        f32x4 e0 = *(const f32x4*)ge, e1 = *(const f32x4*)(ge + 4);
        s16x8 ev;
#pragma unroll
        for (int j = 0; j < 4; j++) { ev[j] = f2bf(e0[j]); ev[4 + j] = f2bf(e1[j]); }
        *(s16x8*)(smem + 8 * 8192 + w * 1024 + lane * 16) = ev;
        if (tid < 128) {
            int2 sd2 = srcdst[p0b + tid];
            dst_s[tid]  = sd2.y;
            cong_s[tid] = f2bf(cong[sd2.x]);
        }
    }
    __syncthreads();

    const int rdoff = m * 64 + ((q ^ ((m >> 1) & 3)) << 4);   // conflict-free A-read offset

    // ---- layer 1: all 128 edges x wave's 32 cols, no barriers ----
    f32x4 acc[8][2];
#pragma unroll
    for (int mt = 0; mt < 8; mt++) {
        acc[mt][0] = (f32x4){0.f, 0.f, 0.f, 0.f};
        acc[mt][1] = (f32x4){0.f, 0.f, 0.f, 0.f};
    }
#pragma unroll
    for (int t = 0; t < 9; t++) {
        const short* bw = W1s + (t * 16 + w * 2) * 512 + lane * 8;
        s16x8 b0 = *(const s16x8*)bw;
        s16x8 b1v = *(const s16x8*)(bw + 512);
#pragma unroll
        for (int mt = 0; mt < 8; mt++) {
            s16x8 a = *(const s16x8*)(smem + t * 8192 + mt * 1024 + rdoff);
            acc[mt][0] = MFMA(a, b0, acc[mt][0]);
            acc[mt][1] = MFMA(a, b1v, acc[mt][1]);
        }
    }
    {   // t=9: congestion feature (k=288) — A synthesized from cong_s
        const short* bw = W1s + (9 * 16 + w * 2) * 512 + lane * 8;
        s16x8 b0 = *(const s16x8*)bw;
        s16x8 b1v = *(const s16x8*)(bw + 512);
#pragma unroll
        for (int mt = 0; mt < 8; mt++) {
            s16x8 a = (s16x8){0, 0, 0, 0, 0, 0, 0, 0};
            short cv = cong_s[mt * 16 + m];
            a[0] = (q == 0) ? cv : (short)0;
            acc[mt][0] = MFMA(a, b0, acc[mt][0]);
            acc[mt][1] = MFMA(a, b1v, acc[mt][1]);
        }
    }
    __syncthreads();      // all A-reads done -> safe to overwrite with h

    // ---- h-write: +bias, relu, bf16 -> LDS chunk w (same swizzled layout) ----
    // row = edge = mt*16 + q*4 + r -> key = (edge>>1)&3 = (2q + (r>>1)) & 3
    {
        float bb0 = b1[w * 32 + m];
        float bb1 = b1[w * 32 + 16 + m];
        short* hbase = (short*)(smem + w * 8192);
#pragma unroll
        for (int mt = 0; mt < 8; mt++) {
#pragma unroll
            for (int r = 0; r < 4; r++) {
                int edge = mt * 16 + q * 4 + r;
                int key  = (2 * q + (r >> 1)) & 3;
                int so0  = (((m >> 3) + 0) ^ key) * 8 + (m & 7);
                int so1  = (((m >> 3) + 2) ^ key) * 8 + (m & 7);
                float v0 = acc[mt][0][r] + bb0;
                float v1 = acc[mt][1][r] + bb1;
                hbase[edge * 32 + so0] = f2bf(v0 > 0.f ? v0 : 0.f);
                hbase[edge * 32 + so1] = f2bf(v1 > 0.f ? v1 : 0.f);
            }
        }
    }
    __syncthreads();

    // ---- layer 2: K=256 over h, wave owns 16 out-cols, no barriers ----
    f32x4 acc2[8];
#pragma unroll
    for (int mt = 0; mt < 8; mt++) acc2[mt] = (f32x4){0.f, 0.f, 0.f, 0.f};
#pragma unroll
    for (int t2 = 0; t2 < 8; t2++) {
        s16x8 b = *(const s16x8*)(W2s + (t2 * 8 + w) * 512 + lane * 8);
#pragma unroll
        for (int mt = 0; mt < 8; mt++) {
            s16x8 a = *(const s16x8*)(smem + t2 * 8192 + mt * 1024 + rdoff);
            acc2[mt] = MFMA(a, b, acc2[mt]);
        }
    }
    __syncthreads();      // h dead -> mbuf may alias

    // ---- messages -> mbuf ----
    {
        float (*mbuf)[132] = (float (*)[132])smem;
        float bb = b2[w * 16 + m];
#pragma unroll
        for (int mt = 0; mt < 8; mt++)
#pragma unroll
            for (int r = 0; r < 4; r++)
                mbuf[mt * 16 + q * 4 + r][w * 16 + m] = acc2[mt][r] + bb;
    }
    __syncthreads();

    // ---- segment-reduce 128 sorted rows (quarters of 32; atomics fix seams) ----
    {
        float (*mbuf)[132] = (float (*)[132])smem;
        const int qtr = tid >> 7, cc = tid & 127;
        float s = 0.f;
        int prev = dst_s[qtr * 32];
        for (int row = qtr * 32; row < qtr * 32 + 32; row++) {
            int dcur = dst_s[row];
            if (dcur != prev) {
                __hip_atomic_fetch_add(agg + (long)prev * D + cc, s,
                                       __ATOMIC_RELAXED, __HIP_MEMORY_SCOPE_AGENT);
                s = 0.f; prev = dcur;
            }
            s += mbuf[row][cc];
        }
        __hip_atomic_fetch_add(agg + (long)prev * D + cc, s,
                               __ATOMIC_RELAXED, __HIP_MEMORY_SCOPE_AGENT);
    }
}

// ---- node MLP: same A-stationary zero-barrier structure, same new swizzle ----
__global__ __launch_bounds__(512, 4)
void k_node(const short* __restrict__ xb, const float* __restrict__ agg,
            const short* __restrict__ U1s, const float* __restrict__ b1,
            const short* __restrict__ U2s, const float* __restrict__ b2,
            float* __restrict__ out) {
    __shared__ char smem[65536];     // A: 8 x [128 rows][64B]; h aliases
    const int tid  = threadIdx.x;
    const int lane = tid & 63;
    const int w    = tid >> 6;
    const int m    = lane & 15;
    const int q    = lane >> 4;
    const int r0   = blockIdx.x * 128;

    {
        int rowl = w * 16 + (lane >> 2);
        int grow = r0 + rowl;
        int gc   = grow < NN ? grow : 0;              // clamp; stores guarded
        int kqs  = (lane & 3) ^ ((lane >> 3) & 3);    // new key
        const char* gx = (const char*)xb + (long)gc * 256 + kqs * 16;
#pragma unroll
        for (int t = 0; t < 4; t++)                   // x: chunks 0..3
            gll16(gx + t * 64, smem + t * 8192 + w * 1024);
        const float* ga = agg + (long)gc * D + kqs * 8;
#pragma unroll
        for (int t = 0; t < 4; t++) {                 // agg (fp32->bf16): chunks 4..7
            f32x4 a0 = *(const f32x4*)(ga + t * 32);
            f32x4 a1 = *(const f32x4*)(ga + t * 32 + 4);
            s16x8 v;
#pragma unroll
            for (int j = 0; j < 4; j++) { v[j] = f2bf(a0[j]); v[4 + j] = f2bf(a1[j]); }
            *(s16x8*)(smem + (4 + t) * 8192 + w * 1024 + lane * 16) = v;
        }
    }
    __syncthreads();

    const int rdoff = m * 64 + ((q ^ ((m >> 1) & 3)) << 4);

    f32x4 acc[8][2];
#pragma unroll
    for (int mt = 0; mt < 8; mt++) {
        acc[mt][0] = (f32x4){0.f, 0.f, 0.f, 0.f};
        acc[mt][1] = (f32x4){0.f, 0.f, 0.f, 0.f};
    }
#pragma unroll
    for (int t = 0; t < 8; t++) {
        const short* bw = U1s + (t * 16 + w * 2) * 512 + lane * 8;
        s16x8 b0 = *(const s16x8*)bw;
        s16x8 b1v = *(const s16x8*)(bw + 512);
#pragma unroll
        for (int mt = 0; mt < 8; mt++) {
            s16x8 a = *(const s16x8*)(smem + t * 8192 + mt * 1024 + rdoff);
            acc[mt][0] = MFMA(a, b0, acc[mt][0]);
            acc[mt][1] = MFMA(a, b1v, acc[mt][1]);
        }
    }
    __syncthreads();

    {
        float bb0 = b1[w * 32 + m];
        float bb1 = b1[w * 32 + 16 + m];
        short* hbase = (short*)(smem + w * 8192);
#pragma unroll
        for (int mt = 0; mt < 8; mt++) {
#pragma unroll
            for (int r = 0; r < 4; r++) {
                int row = mt * 16 + q * 4 + r;
                int key = (2 * q + (r >> 1)) & 3;
                int so0 = (((m >> 3) + 0) ^ key) * 8 + (m & 7);
                int so1 = (((m >> 3) + 2) ^ key) * 8 + (m & 7);
                float v0 = acc[mt][0][r] + bb0;
                float v1 = acc[mt][1][r] + bb1;
                hbase[row * 32 + so0] = f2bf(v0 > 0.f ? v0 : 0.f);
                hbase[row * 32 + so1] = f2bf(v1 > 0.f ? v1 : 0.f);
            }
        }
    }
    __syncthreads();

    f32x4 acc2[8];
#pragma unroll
    for (int mt = 0; mt < 8; mt++) acc2[mt] = (f32x4){0.f, 0.f, 0.f, 0.f};
#pragma unroll
    for (int t2 = 0; t2 < 8; t2++) {
        s16x8 b = *(const s16x8*)(U2s + (t2 * 8 + w) * 512 + lane * 8);
#pragma unroll
        for (int mt = 0; mt < 8; mt++) {
            s16x8 a = *(const s16x8*)(smem + t2 * 8192 + mt * 1024 + rdoff);
            acc2[mt] = MFMA(a, b, acc2[mt]);
        }
    }

    {
        float bb = b2[w * 16 + m];
#pragma unroll
        for (int mt = 0; mt < 8; mt++)
#pragma unroll
            for (int r = 0; r < 4; r++) {
                int grow = r0 + mt * 16 + q * 4 + r;
                if (grow < NN)
                    out[(long)grow * D + w * 16 + m] = acc2[mt][r] + bb;
            }
    }
}

extern "C" void kernel_launch(void* const* d_in, const int* in_sizes, int n_in,
                              void* d_out, int out_size, void* d_ws, size_t ws_size,
                              hipStream_t stream) {
    const float* x     = (const float*)d_in[0];
    const int*   ei    = (const int*)d_in[1];
    const float* eattr = (const float*)d_in[2];
    const float* cong  = (const float*)d_in[3];
    const float* mW1   = (const float*)d_in[4];
    const float* mb1   = (const float*)d_in[5];
    const float* mW2   = (const float*)d_in[6];
    const float* mb2   = (const float*)d_in[7];
    const float* uW1   = (const float*)d_in[8];
    const float* ub1   = (const float*)d_in[9];
    const float* uW2   = (const float*)d_in[10];
    const float* ub2   = (const float*)d_in[11];

    char* ws = (char*)d_ws;
    float* agg    = (float*)ws;                     // 51,200,000 B
    short* xb     = (short*)(ws + 51200000);        // 25,600,000 B
    short* W1s    = (short*)(ws + 76800000);        //    163,840 B (K padded 289->320)
    short* W2s    = (short*)(ws + 76963840);        //     65,536 B
    short* U1s    = (short*)(ws + 77029376);        //    131,072 B
    short* U2s    = (short*)(ws + 77160448);        //     65,536 B
    int*   cnt    = (int*)(ws + 77225984);          //    400,000 B (cursor after scan)
    int*   perm   = (int*)(ws + 77625984);          //  6,400,000 B
    int2*  srcdst = (int2*)(ws + 84025984);         // 12,800,000 B
    int*   psum   = (int*)(ws + 96825984);          //        512 B (block partials)

    hipMemsetAsync(agg, 0, (size_t)NN * D * sizeof(float), stream);
    hipMemsetAsync(cnt, 0, (size_t)NN * sizeof(int), stream);

    k_cvt_x<<<(NN * D / 4 + 255) / 256, 256, 0, stream>>>(x, xb, NN * D);

    int tW1 = 10 * 16 * 512, tW2 = 8 * 8 * 512, tU1 = 8 * 16 * 512, tU2 = 8 * 8 * 512;
    k_swz<<<(tW1 + 255) / 256, 256, 0, stream>>>(mW1, W1s, 289, 256, tW1);
    k_swz<<<(tW2 + 255) / 256, 256, 0, stream>>>(mW2, W2s, 256, 128, tW2);
    k_swz<<<(tU1 + 255) / 256, 256, 0, stream>>>(uW1, U1s, 256, 256, tU1);
    k_swz<<<(tU2 + 255) / 256, 256, 0, stream>>>(uW2, U2s, 256, 128, tU2);

    // counting sort by dst (hierarchical scan)
    int nb = (NN + 1023) / 1024;   // 98
    k_hist<<<(E_TOTAL + 255) / 256, 256, 0, stream>>>(ei, cnt);
    k_scan1<<<nb, 1024, 0, stream>>>(cnt, psum, NN);
    k_scan2<<<1, 128, 0, stream>>>(psum, nb);
    k_scan3<<<nb, 1024, 0, stream>>>(psum, cnt, NN);
    k_perm<<<(E_TOTAL + 255) / 256, 256, 0, stream>>>(ei, cnt, perm, srcdst);

    // 128 sorted edges per 512-thread block (8 waves, N-split)
    k_edge<<<E_TOTAL / 128, 512, 0, stream>>>(xb, perm, srcdst, eattr, cong,
                                              W1s, mb1, W2s, mb2, agg);
    // 128 rows per 512-thread block
    k_node<<<(NN + 127) / 128, 512, 0, stream>>>(xb, agg, U1s, ub1, U2s, ub2,
                                                 (float*)d_out);
}

// Round 8
// 935.479 us; speedup vs baseline: 1.1275x; 1.0123x over previous
//
#include <hip/hip_runtime.h>

#define E_TOTAL 1600000
#define NN 100000
#define D 128      // node dim
#define ED 32      // edge dim
#define H 256      // hidden dim

typedef __attribute__((ext_vector_type(8))) short s16x8;   // 8 bf16 (one MFMA A/B frag)
typedef __attribute__((ext_vector_type(4))) short s16x4;
typedef __attribute__((ext_vector_type(4))) float f32x4;

#define MFMA(a, b, c) __builtin_amdgcn_mfma_f32_16x16x32_bf16((a), (b), (c), 0, 0, 0)

__device__ __forceinline__ short f2bf(float f) {
    unsigned u = __builtin_bit_cast(unsigned, f);
    u += 0x7fffu + ((u >> 16) & 1u);   // round-to-nearest-even
    return (short)(u >> 16);
}

// async global->LDS, 16B per lane; LDS dest is wave-uniform base (HW adds lane*16)
__device__ __forceinline__ void gll16(const void* g, void* l) {
    __builtin_amdgcn_global_load_lds(
        (const __attribute__((address_space(1))) void*)g,
        (__attribute__((address_space(3))) void*)l, 16, 0, 0);
}

// ---- prep: fp32 x -> bf16 ----
__global__ void k_cvt_x(const float* __restrict__ x, short* __restrict__ xb, int n) {
    int i = (blockIdx.x * blockDim.x + threadIdx.x) * 4;
    if (i >= n) return;
    f32x4 v = *(const f32x4*)(x + i);
    s16x4 o;
    o[0] = f2bf(v[0]); o[1] = f2bf(v[1]); o[2] = f2bf(v[2]); o[3] = f2bf(v[3]);
    *(s16x4*)(xb + i) = o;
}

// ---- prep: swizzle weight [K][N] fp32 into MFMA B-fragment order, bf16 ----
__global__ void k_swz(const float* __restrict__ W, short* __restrict__ out,
                      int K, int N, int total) {
    int idx = blockIdx.x * blockDim.x + threadIdx.x;
    if (idx >= total) return;
    int j    = idx & 7;
    int lane = (idx >> 3) & 63;
    int rest = idx >> 9;                // t*NT + nt
    int NT   = N >> 4;
    int nt   = rest % NT;
    int t    = rest / NT;
    int k    = t * 32 + (lane >> 4) * 8 + j;
    int col  = nt * 16 + (lane & 15);
    float v  = (k < K) ? W[k * N + col] : 0.f;
    out[idx] = f2bf(v);
}

// ---- sort prep: histogram of dst ----
__global__ void k_hist(const int* __restrict__ ei, int* __restrict__ cnt) {
    int e = blockIdx.x * blockDim.x + threadIdx.x;
    if (e >= E_TOTAL) return;
    atomicAdd(&cnt[ei[E_TOTAL + e]], 1);
}

// ---- hierarchical scan: per-block exclusive scan + block totals ----
__global__ void k_scan1(int* __restrict__ cnt, int* __restrict__ psum, int n) {
    __shared__ int wsum[16];
    __shared__ int woff[16];
    const int tid = threadIdx.x, lane = tid & 63, wv = tid >> 6;
    int i = blockIdx.x * 1024 + tid;
    int v = (i < n) ? cnt[i] : 0;
    int s = v;
#pragma unroll
    for (int off = 1; off < 64; off <<= 1) {
        int u = __shfl_up(s, off, 64);
        if (lane >= off) s += u;
    }
    if (lane == 63) wsum[wv] = s;
    __syncthreads();
    if (wv == 0 && lane < 16) {
        int t = wsum[lane];
        int sc = t;
#pragma unroll
        for (int off = 1; off < 16; off <<= 1) {
            int u = __shfl_up(sc, off, 16);
            if (lane >= off) sc += u;
        }
        woff[lane] = sc - t;
    }
    __syncthreads();
    int excl = (s - v) + woff[wv];
    if (i < n) cnt[i] = excl;
    if (tid == 1023) psum[blockIdx.x] = excl + v;   // block total
}

// ---- scan the block totals (one small block) ----
__global__ void k_scan2(int* __restrict__ psum, int nb) {
    __shared__ int w0;
    const int tid = threadIdx.x, lane = tid & 63, wv = tid >> 6;
    int v = (tid < nb) ? psum[tid] : 0;
    int s = v;
#pragma unroll
    for (int off = 1; off < 64; off <<= 1) {
        int u = __shfl_up(s, off, 64);
        if (lane >= off) s += u;
    }
    if (wv == 0 && lane == 63) w0 = s;
    __syncthreads();
    int excl = (s - v) + (wv ? w0 : 0);
    if (tid < nb) psum[tid] = excl;
}

// ---- add block offsets back ----
__global__ void k_scan3(const int* __restrict__ psum, int* __restrict__ cnt, int n) {
    int i = blockIdx.x * 1024 + threadIdx.x;
    if (i < n) cnt[i] += psum[blockIdx.x];
}

// ---- sort prep: scatter edges into dst-sorted order ----
__global__ void k_perm(const int* __restrict__ ei, int* __restrict__ cursor,
                       int* __restrict__ perm, int2* __restrict__ srcdst) {
    int e = blockIdx.x * blockDim.x + threadIdx.x;
    if (e >= E_TOTAL) return;
    int s = ei[e], d = ei[E_TOTAL + e];
    int pos = atomicAdd(&cursor[d], 1);
    perm[pos] = e;
    srcdst[pos] = make_int2(s, d);
}

// ---- edge MLP + segment-reduced scatter-add: A-stationary, 64x64 wave tiles ----
// 512 thr / 8 waves / 128 sorted edges per block. Wave w = (eh=w>>2, cg=w&3)
// owns a 64-edge x 64-col tile of layer 1 (acc[4][4] = 64 regs, SAME as R7)
// and 64-edge x 32-col of layer 2. Each wave reads only HALF the A image and
// each A-read feeds 4 MFMAs -> block LDS A-reads 1088 -> 544 b128, at R7's
// occupancy (8 waves, 74.75KB LDS, 2 blocks/CU). W1/W2 read twice per block
// (once per edge-half) — L1-resident, cheap. Conflict-free swizzle unchanged.
__global__ __launch_bounds__(512, 4)
void k_edge(const short* __restrict__ xb, const int* __restrict__ perm,
            const int2* __restrict__ srcdst,
            const float* __restrict__ eattr, const float* __restrict__ cong,
            const short* __restrict__ W1s, const float* __restrict__ b1,
            const short* __restrict__ W2s, const float* __restrict__ b2,
            float* __restrict__ agg) {
    __shared__ char smem[73728];     // A: 9 x [128 edges][64B]; h + mbuf alias it
    __shared__ int   dst_s[128];
    __shared__ short cong_s[128];

    const int tid  = threadIdx.x;
    const int lane = tid & 63;
    const int w    = tid >> 6;       // wave 0..7
    const int eh   = w >> 2;         // edge half (0/1): rows [eh*64, eh*64+64)
    const int cg   = w & 3;          // col group: l1 cols [cg*64,+64), l2 [cg*32,+32)
    const int m    = lane & 15;
    const int q    = lane >> 4;
    const int p0b  = blockIdx.x * 128;

    // ---- stage A (once per block; staging map independent of compute map) ----
    {
        int edge = w * 16 + (lane >> 2);              // wave w stages rows w*16..+16
        int2 sd  = srcdst[p0b + edge];
        int kqs  = (lane & 3) ^ ((lane >> 3) & 3);    // pre-swizzled source slot
        const char* gx0 = (const char*)xb + (long)sd.x * 256 + kqs * 16;
        const char* gx1 = (const char*)xb + (long)sd.y * 256 + kqs * 16;
#pragma unroll
        for (int t = 0; t < 4; t++)                   // x[src]: chunks 0..3
            gll16(gx0 + t * 64, smem + t * 8192 + w * 1024);
#pragma unroll
        for (int t = 0; t < 4; t++)                   // x[dst]: chunks 4..7
            gll16(gx1 + t * 64, smem + (4 + t) * 8192 + w * 1024);
        // chunk 8: eattr (fp32 -> bf16 via regs)
        int ea = perm[p0b + edge];
        const float* ge = eattr + (long)ea * ED + kqs * 8;
        f32x4 e0 = *(const f32x4*)ge, e1 = *(const f32x4*)(ge + 4);
        s16x8 ev;
#pragma unroll
        for (int j = 0; j < 4; j++) { ev[j] = f2bf(e0[j]); ev[4 + j] = f2bf(e1[j]); }
        *(s16x8*)(smem + 8 * 8192 + w * 1024 + lane * 16) = ev;
        if (tid < 128) {
            int2 sd2 = srcdst[p0b + tid];
            dst_s[tid]  = sd2.y;
            cong_s[tid] = f2bf(cong[sd2.x]);
        }
    }
    __syncthreads();

    const int rdoff = m * 64 + ((q ^ ((m >> 1) & 3)) << 4);   // conflict-free A-read offset

    // ---- layer 1: 64 edges x 64 cols per wave, no barriers ----
    f32x4 acc[4][4];
#pragma unroll
    for (int mt = 0; mt < 4; mt++)
#pragma unroll
        for (int n = 0; n < 4; n++) acc[mt][n] = (f32x4){0.f, 0.f, 0.f, 0.f};

#pragma unroll
    for (int t = 0; t < 9; t++) {
        s16x8 b[4];
        const short* bw = W1s + (t * 16 + cg * 4) * 512 + lane * 8;
#pragma unroll
        for (int n = 0; n < 4; n++) b[n] = *(const s16x8*)(bw + n * 512);
#pragma unroll
        for (int mt = 0; mt < 4; mt++) {
            s16x8 a = *(const s16x8*)(smem + t * 8192 + (eh * 4 + mt) * 1024 + rdoff);
#pragma unroll
            for (int n = 0; n < 4; n++) acc[mt][n] = MFMA(a, b[n], acc[mt][n]);
        }
    }
    {   // t=9: congestion feature (k=288) — A synthesized from cong_s
        s16x8 b[4];
        const short* bw = W1s + (9 * 16 + cg * 4) * 512 + lane * 8;
#pragma unroll
        for (int n = 0; n < 4; n++) b[n] = *(const s16x8*)(bw + n * 512);
#pragma unroll
        for (int mt = 0; mt < 4; mt++) {
            s16x8 a = (s16x8){0, 0, 0, 0, 0, 0, 0, 0};
            short cv = cong_s[eh * 64 + mt * 16 + m];
            a[0] = (q == 0) ? cv : (short)0;
#pragma unroll
            for (int n = 0; n < 4; n++) acc[mt][n] = MFMA(a, b[n], acc[mt][n]);
        }
    }
    __syncthreads();      // all A-reads done -> safe to overwrite with h

    // ---- h-write: +bias, relu, bf16 -> col-chunks 2cg,2cg+1, rows eh*64..+64 ----
    // h chunk c covers cols [c*32,+32); col = cg*64 + n*16 + m -> c = 2cg+(n>>1),
    // slot srq = (n&1)*2 + (m>>3); edge = eh*64 + mt*16 + q*4 + r,
    // key = (edge>>1)&3 = (2q + (r>>1)) & 3.
    {
        short* hb16 = (short*)smem;
#pragma unroll
        for (int n = 0; n < 4; n++) {
            const int chunk = 2 * cg + (n >> 1);
            const int srq   = (n & 1) * 2 + (m >> 3);
            const float bias = b1[cg * 64 + n * 16 + m];
#pragma unroll
            for (int mt = 0; mt < 4; mt++) {
#pragma unroll
                for (int r = 0; r < 4; r++) {
                    int edge = eh * 64 + mt * 16 + q * 4 + r;
                    int key  = (2 * q + (r >> 1)) & 3;
                    int phys = srq ^ key;
                    float v  = acc[mt][n][r] + bias;
                    hb16[chunk * 4096 + edge * 32 + phys * 8 + (m & 7)] =
                        f2bf(v > 0.f ? v : 0.f);
                }
            }
        }
    }
    __syncthreads();

    // ---- layer 2: K=256 over h; 64 edges x 32 cols per wave, no barriers ----
    f32x4 acc2[4][2];
#pragma unroll
    for (int mt = 0; mt < 4; mt++) {
        acc2[mt][0] = (f32x4){0.f, 0.f, 0.f, 0.f};
        acc2[mt][1] = (f32x4){0.f, 0.f, 0.f, 0.f};
    }
#pragma unroll
    for (int t2 = 0; t2 < 8; t2++) {
        const short* bw = W2s + (t2 * 8 + cg * 2) * 512 + lane * 8;
        s16x8 b0  = *(const s16x8*)bw;
        s16x8 b1v = *(const s16x8*)(bw + 512);
#pragma unroll
        for (int mt = 0; mt < 4; mt++) {
            s16x8 a = *(const s16x8*)(smem + t2 * 8192 + (eh * 4 + mt) * 1024 + rdoff);
            acc2[mt][0] = MFMA(a, b0, acc2[mt][0]);
            acc2[mt][1] = MFMA(a, b1v, acc2[mt][1]);
        }
    }
    __syncthreads();      // h dead -> mbuf may alias

    // ---- messages -> mbuf ----
    {
        float (*mbuf)[132] = (float (*)[132])smem;
        float bb0 = b2[cg * 32 + m];
        float bb1 = b2[cg * 32 + 16 + m];
#pragma unroll
        for (int mt = 0; mt < 4; mt++)
#pragma unroll
            for (int r = 0; r < 4; r++) {
                int edge = eh * 64 + mt * 16 + q * 4 + r;
                mbuf[edge][cg * 32 + m]      = acc2[mt][0][r] + bb0;
                mbuf[edge][cg * 32 + 16 + m] = acc2[mt][1][r] + bb1;
            }
    }
    __syncthreads();

    // ---- segment-reduce 128 sorted rows (quarters of 32; atomics fix seams) ----
    {
        float (*mbuf)[132] = (float (*)[132])smem;
        const int qtr = tid >> 7, cc = tid & 127;
        float s = 0.f;
        int prev = dst_s[qtr * 32];
        for (int row = qtr * 32; row < qtr * 32 + 32; row++) {
            int dcur = dst_s[row];
            if (dcur != prev) {
                __hip_atomic_fetch_add(agg + (long)prev * D + cc, s,
                                       __ATOMIC_RELAXED, __HIP_MEMORY_SCOPE_AGENT);
                s = 0.f; prev = dcur;
            }
            s += mbuf[row][cc];
        }
        __hip_atomic_fetch_add(agg + (long)prev * D + cc, s,
                               __ATOMIC_RELAXED, __HIP_MEMORY_SCOPE_AGENT);
    }
}

// ---- node MLP: same 64x64 wave-tile structure ----
__global__ __launch_bounds__(512, 4)
void k_node(const short* __restrict__ xb, const float* __restrict__ agg,
            const short* __restrict__ U1s, const float* __restrict__ b1,
            const short* __restrict__ U2s, const float* __restrict__ b2,
            float* __restrict__ out) {
    __shared__ char smem[65536];     // A: 8 x [128 rows][64B]; h aliases
    const int tid  = threadIdx.x;
    const int lane = tid & 63;
    const int w    = tid >> 6;
    const int eh   = w >> 2;
    const int cg   = w & 3;
    const int m    = lane & 15;
    const int q    = lane >> 4;
    const int r0   = blockIdx.x * 128;

    {
        int rowl = w * 16 + (lane >> 2);
        int grow = r0 + rowl;
        int gc   = grow < NN ? grow : 0;              // clamp; stores guarded
        int kqs  = (lane & 3) ^ ((lane >> 3) & 3);
        const char* gx = (const char*)xb + (long)gc * 256 + kqs * 16;
#pragma unroll
        for (int t = 0; t < 4; t++)                   // x: chunks 0..3
            gll16(gx + t * 64, smem + t * 8192 + w * 1024);
        const float* ga = agg + (long)gc * D + kqs * 8;
#pragma unroll
        for (int t = 0; t < 4; t++) {                 // agg (fp32->bf16): chunks 4..7
            f32x4 a0 = *(const f32x4*)(ga + t * 32);
            f32x4 a1 = *(const f32x4*)(ga + t * 32 + 4);
            s16x8 v;
#pragma unroll
            for (int j = 0; j < 4; j++) { v[j] = f2bf(a0[j]); v[4 + j] = f2bf(a1[j]); }
            *(s16x8*)(smem + (4 + t) * 8192 + w * 1024 + lane * 16) = v;
        }
    }
    __syncthreads();

    const int rdoff = m * 64 + ((q ^ ((m >> 1) & 3)) << 4);

    f32x4 acc[4][4];
#pragma unroll
    for (int mt = 0; mt < 4; mt++)
#pragma unroll
        for (int n = 0; n < 4; n++) acc[mt][n] = (f32x4){0.f, 0.f, 0.f, 0.f};

#pragma unroll
    for (int t = 0; t < 8; t++) {
        s16x8 b[4];
        const short* bw = U1s + (t * 16 + cg * 4) * 512 + lane * 8;
#pragma unroll
        for (int n = 0; n < 4; n++) b[n] = *(const s16x8*)(bw + n * 512);
#pragma unroll
        for (int mt = 0; mt < 4; mt++) {
            s16x8 a = *(const s16x8*)(smem + t * 8192 + (eh * 4 + mt) * 1024 + rdoff);
#pragma unroll
            for (int n = 0; n < 4; n++) acc[mt][n] = MFMA(a, b[n], acc[mt][n]);
        }
    }
    __syncthreads();

    {
        short* hb16 = (short*)smem;
#pragma unroll
        for (int n = 0; n < 4; n++) {
            const int chunk = 2 * cg + (n >> 1);
            const int srq   = (n & 1) * 2 + (m >> 3);
            const float bias = b1[cg * 64 + n * 16 + m];
#pragma unroll
            for (int mt = 0; mt < 4; mt++) {
#pragma unroll
                for (int r = 0; r < 4; r++) {
                    int row = eh * 64 + mt * 16 + q * 4 + r;
                    int key = (2 * q + (r >> 1)) & 3;
                    int phys = srq ^ key;
                    float v = acc[mt][n][r] + bias;
                    hb16[chunk * 4096 + row * 32 + phys * 8 + (m & 7)] =
                        f2bf(v > 0.f ? v : 0.f);
                }
            }
        }
    }
    __syncthreads();

    f32x4 acc2[4][2];
#pragma unroll
    for (int mt = 0; mt < 4; mt++) {
        acc2[mt][0] = (f32x4){0.f, 0.f, 0.f, 0.f};
        acc2[mt][1] = (f32x4){0.f, 0.f, 0.f, 0.f};
    }
#pragma unroll
    for (int t2 = 0; t2 < 8; t2++) {
        const short* bw = U2s + (t2 * 8 + cg * 2) * 512 + lane * 8;
        s16x8 b0  = *(const s16x8*)bw;
        s16x8 b1v = *(const s16x8*)(bw + 512);
#pragma unroll
        for (int mt = 0; mt < 4; mt++) {
            s16x8 a = *(const s16x8*)(smem + t2 * 8192 + (eh * 4 + mt) * 1024 + rdoff);
            acc2[mt][0] = MFMA(a, b0, acc2[mt][0]);
            acc2[mt][1] = MFMA(a, b1v, acc2[mt][1]);
        }
    }

    {
        float bb0 = b2[cg * 32 + m];
        float bb1 = b2[cg * 32 + 16 + m];
#pragma unroll
        for (int mt = 0; mt < 4; mt++)
#pragma unroll
            for (int r = 0; r < 4; r++) {
                int grow = r0 + eh * 64 + mt * 16 + q * 4 + r;
                if (grow < NN) {
                    out[(long)grow * D + cg * 32 + m]      = acc2[mt][0][r] + bb0;
                    out[(long)grow * D + cg * 32 + 16 + m] = acc2[mt][1][r] + bb1;
                }
            }
    }
}

extern "C" void kernel_launch(void* const* d_in, const int* in_sizes, int n_in,
                              void* d_out, int out_size, void* d_ws, size_t ws_size,
                              hipStream_t stream) {
    const float* x     = (const float*)d_in[0];
    const int*   ei    = (const int*)d_in[1];
    const float* eattr = (const float*)d_in[2];
    const float* cong  = (const float*)d_in[3];
    const float* mW1   = (const float*)d_in[4];
    const float* mb1   = (const float*)d_in[5];
    const float* mW2   = (const float*)d_in[6];
    const float* mb2   = (const float*)d_in[7];
    const float* uW1   = (const float*)d_in[8];
    const float* ub1   = (const float*)d_in[9];
    const float* uW2   = (const float*)d_in[10];
    const float* ub2   = (const float*)d_in[11];

    char* ws = (char*)d_ws;
    float* agg    = (float*)ws;                     // 51,200,000 B
    short* xb     = (short*)(ws + 51200000);        // 25,600,000 B
    short* W1s    = (short*)(ws + 76800000);        //    163,840 B (K padded 289->320)
    short* W2s    = (short*)(ws + 76963840);        //     65,536 B
    short* U1s    = (short*)(ws + 77029376);        //    131,072 B
    short* U2s    = (short*)(ws + 77160448);        //     65,536 B
    int*   cnt    = (int*)(ws + 77225984);          //    400,000 B (cursor after scan)
    int*   perm   = (int*)(ws + 77625984);          //  6,400,000 B
    int2*  srcdst = (int2*)(ws + 84025984);         // 12,800,000 B
    int*   psum   = (int*)(ws + 96825984);          //        512 B (block partials)

    hipMemsetAsync(agg, 0, (size_t)NN * D * sizeof(float), stream);
    hipMemsetAsync(cnt, 0, (size_t)NN * sizeof(int), stream);

    k_cvt_x<<<(NN * D / 4 + 255) / 256, 256, 0, stream>>>(x, xb, NN * D);

    int tW1 = 10 * 16 * 512, tW2 = 8 * 8 * 512, tU1 = 8 * 16 * 512, tU2 = 8 * 8 * 512;
    k_swz<<<(tW1 + 255) / 256, 256, 0, stream>>>(mW1, W1s, 289, 256, tW1);
    k_swz<<<(tW2 + 255) / 256, 256, 0, stream>>>(mW2, W2s, 256, 128, tW2);
    k_swz<<<(tU1 + 255) / 256, 256, 0, stream>>>(uW1, U1s, 256, 256, tU1);
    k_swz<<<(tU2 + 255) / 256, 256, 0, stream>>>(uW2, U2s, 256, 128, tU2);

    // counting sort by dst (hierarchical scan)
    int nb = (NN + 1023) / 1024;   // 98
    k_hist<<<(E_TOTAL + 255) / 256, 256, 0, stream>>>(ei, cnt);
    k_scan1<<<nb, 1024, 0, stream>>>(cnt, psum, NN);
    k_scan2<<<1, 128, 0, stream>>>(psum, nb);
    k_scan3<<<nb, 1024, 0, stream>>>(psum, cnt, NN);
    k_perm<<<(E_TOTAL + 255) / 256, 256, 0, stream>>>(ei, cnt, perm, srcdst);

    // 128 sorted edges per 512-thread block (8 waves, 64x64 tiles)
    k_edge<<<E_TOTAL / 128, 512, 0, stream>>>(xb, perm, srcdst, eattr, cong,
                                              W1s, mb1, W2s, mb2, agg);
    // 128 rows per 512-thread block
    k_node<<<(NN + 127) / 128, 512, 0, stream>>>(xb, agg, U1s, ub1, U2s, ub2,
                                                 (float*)d_out);
}